// Round 1
// baseline (6361.246 us; speedup 1.0000x reference)
//
#include <hip/hip_runtime.h>
#include <math.h>

#define BB 64
#define TT 40
#define NB 36
#define FS 1024
#define WS 512
#define HS 512
#define VOC 10000
#define STEPN 20
#define THRC 0.2f

// ---------------------------------------------------------------------------
// Generic fp32 GEMM: C[M,N] = A[M,K](lda) @ W[K,N](ldb) + bias (+ C if accum)
// optional tanh. 64x64 tile, BK=16, 256 threads, 4x4 microtile.
// ---------------------------------------------------------------------------
#define GBM 64
#define GBN 64
#define GBK 16

__global__ void gemm_kernel(const float* __restrict__ A, int lda,
                            const float* __restrict__ W, int ldb,
                            const float* __restrict__ bias,
                            float* __restrict__ C, int ldc,
                            int M, int N, int K, int flags)  // bit0=tanh bit1=accum
{
    __shared__ float As[GBK][GBM + 1];
    __shared__ float Bs[GBK][GBN + 1];
    const int bm = blockIdx.y * GBM;
    const int bn = blockIdx.x * GBN;
    const int tid = threadIdx.x;
    const int tx = tid & 15, ty = tid >> 4;
    float acc[4][4] = {};
    for (int k0 = 0; k0 < K; k0 += GBK) {
#pragma unroll
        for (int i = 0; i < 4; ++i) {
            int idx = tid + i * 256;            // 0..1023
            int m = idx / GBK, k = idx % GBK;
            int gm = bm + m, gk = k0 + k;
            As[k][m] = (gm < M && gk < K) ? A[(size_t)gm * lda + gk] : 0.f;
        }
#pragma unroll
        for (int i = 0; i < 4; ++i) {
            int idx = tid + i * 256;
            int k = idx / GBN, n = idx % GBN;
            int gk = k0 + k, gn = bn + n;
            Bs[k][n] = (gk < K && gn < N) ? W[(size_t)gk * ldb + gn] : 0.f;
        }
        __syncthreads();
#pragma unroll
        for (int k = 0; k < GBK; ++k) {
            float a[4], b[4];
#pragma unroll
            for (int i = 0; i < 4; ++i) a[i] = As[k][ty * 4 + i];
#pragma unroll
            for (int j = 0; j < 4; ++j) b[j] = Bs[k][tx * 4 + j];
#pragma unroll
            for (int i = 0; i < 4; ++i)
#pragma unroll
                for (int j = 0; j < 4; ++j) acc[i][j] += a[i] * b[j];
        }
        __syncthreads();
    }
#pragma unroll
    for (int i = 0; i < 4; ++i) {
        int gm = bm + ty * 4 + i;
        if (gm >= M) continue;
#pragma unroll
        for (int j = 0; j < 4; ++j) {
            int gn = bn + tx * 4 + j;
            if (gn >= N) continue;
            float v = acc[i][j] + (bias ? bias[gn] : 0.f);
            size_t oi = (size_t)gm * ldc + gn;
            if (flags & 2) v += C[oi];
            if (flags & 1) v = tanhf(v);
            C[oi] = v;
        }
    }
}

// ---------------------------------------------------------------------------
// Fused spatial logits: logits[m] = sum_n sp_w[n]*tanh(obj@Wk + bk + q[b])[m,n]
// M=92160 (b = m/1440), N=512, K=1024. logits must be zeroed beforehand.
// ---------------------------------------------------------------------------
__global__ void gemm_spatial_kernel(const float* __restrict__ A,   // obj (M,1024)
                                    const float* __restrict__ W,   // sp_Wk (1024,512)
                                    const float* __restrict__ bk,  // (512)
                                    const float* __restrict__ q,   // (64,512) incl bq
                                    const float* __restrict__ w,   // (512)
                                    float* __restrict__ logits)    // (92160)
{
    __shared__ float As[GBK][GBM + 1];
    __shared__ float Bs[GBK][GBN + 1];
    __shared__ float row_sum[GBM];
    const int bm = blockIdx.y * GBM;
    const int bn = blockIdx.x * GBN;
    const int tid = threadIdx.x;
    const int tx = tid & 15, ty = tid >> 4;
    float acc[4][4] = {};
    for (int k0 = 0; k0 < 1024; k0 += GBK) {
#pragma unroll
        for (int i = 0; i < 4; ++i) {
            int idx = tid + i * 256;
            int m = idx / GBK, k = idx % GBK;
            As[k][m] = A[(size_t)(bm + m) * 1024 + (k0 + k)];
        }
#pragma unroll
        for (int i = 0; i < 4; ++i) {
            int idx = tid + i * 256;
            int k = idx / GBN, n = idx % GBN;
            Bs[k][n] = W[(size_t)(k0 + k) * 512 + (bn + n)];
        }
        __syncthreads();
#pragma unroll
        for (int k = 0; k < GBK; ++k) {
            float a[4], b[4];
#pragma unroll
            for (int i = 0; i < 4; ++i) a[i] = As[k][ty * 4 + i];
#pragma unroll
            for (int j = 0; j < 4; ++j) b[j] = Bs[k][tx * 4 + j];
#pragma unroll
            for (int i = 0; i < 4; ++i)
#pragma unroll
                for (int j = 0; j < 4; ++j) acc[i][j] += a[i] * b[j];
        }
        __syncthreads();
    }
    for (int i = tid; i < GBM; i += 256) row_sum[i] = 0.f;
    __syncthreads();
#pragma unroll
    for (int i = 0; i < 4; ++i) {
        int gm = bm + ty * 4 + i;
        int b = gm / (TT * NB);
        float p = 0.f;
#pragma unroll
        for (int j = 0; j < 4; ++j) {
            int gn = bn + tx * 4 + j;
            p += w[gn] * tanhf(acc[i][j] + bk[gn] + q[b * HS + gn]);
        }
        atomicAdd(&row_sum[ty * 4 + i], p);
    }
    __syncthreads();
    if (tid < GBM) atomicAdd(&logits[bm + tid], row_sum[tid]);
}

// ---------------------------------------------------------------------------
// Per-frame box softmax + weighted sum: one block per bt (2560 blocks)
// ---------------------------------------------------------------------------
__global__ void spatial_attn_kernel(const float* __restrict__ logits, // (2560*36)
                                    const float* __restrict__ obj,    // (92160,1024)
                                    float* __restrict__ obj_att)      // (2560,1024)
{
    int bt = blockIdx.x, tid = threadIdx.x;
    __shared__ float a[NB];
    if (tid < NB) a[tid] = logits[bt * NB + tid];
    __syncthreads();
    if (tid == 0) {
        float m = -1e30f;
        for (int n = 0; n < NB; ++n) m = fmaxf(m, a[n]);
        float s = 0.f;
        for (int n = 0; n < NB; ++n) { a[n] = expf(a[n] - m); s += a[n]; }
        float inv = 1.f / s;
        for (int n = 0; n < NB; ++n) a[n] *= inv;
    }
    __syncthreads();
    for (int d = tid; d < FS; d += 256) {
        float acc = 0.f;
        for (int n = 0; n < NB; ++n)
            acc += a[n] * obj[((size_t)bt * NB + n) * FS + d];
        obj_att[(size_t)bt * FS + d] = acc;
    }
}

// ---------------------------------------------------------------------------
// Fused additive alignment: per (b,s) block. q,kp include their biases.
// out[bs, 0:D] (stride ldo) = softmax_t( w . tanh(q_bs + kp_bt) ) @ Km
// ---------------------------------------------------------------------------
__global__ void align_kernel(const float* __restrict__ q,   // (B*20,512)
                             const float* __restrict__ kp,  // (B*Tn,512)
                             const float* __restrict__ w,   // (512)
                             const float* __restrict__ Km,  // (B*Tn,D)
                             int D, float* __restrict__ out, int ldo, int Tn)
{
    int bs = blockIdx.x;
    int b = bs / STEPN;
    int tid = threadIdx.x, wave = tid >> 6, lane = tid & 63;
    __shared__ float lg[64];
    const float* qrow = q + (size_t)bs * HS;
    for (int t = wave; t < Tn; t += 4) {
        const float* krow = kp + (size_t)(b * Tn + t) * HS;
        float s = 0.f;
        for (int h = lane; h < HS; h += 64)
            s += w[h] * tanhf(qrow[h] + krow[h]);
        for (int off = 32; off > 0; off >>= 1) s += __shfl_down(s, off, 64);
        if (lane == 0) lg[t] = s;
    }
    __syncthreads();
    if (tid == 0) {
        float m = -1e30f;
        for (int t = 0; t < Tn; ++t) m = fmaxf(m, lg[t]);
        float s = 0.f;
        for (int t = 0; t < Tn; ++t) { lg[t] = expf(lg[t] - m); s += lg[t]; }
        float inv = 1.f / s;
        for (int t = 0; t < Tn; ++t) lg[t] *= inv;
    }
    __syncthreads();
    for (int d = tid; d < D; d += 256) {
        float acc = 0.f;
        for (int t = 0; t < Tn; ++t)
            acc += lg[t] * Km[(size_t)(b * Tn + t) * D + d];
        out[(size_t)bs * ldo + d] = acc;
    }
}

// ---------------------------------------------------------------------------
// phr_masks NMS: one block per batch
// ---------------------------------------------------------------------------
__global__ void phr_mask_kernel(const float* __restrict__ P, int* __restrict__ masks)
{
    int b = blockIdx.x, tid = threadIdx.x;
    __shared__ float A[STEPN][STEPN];
    __shared__ float Asum[STEPN];
    const float* Pb = P + (size_t)b * STEPN * STEPN;
    for (int idx = tid; idx < STEPN * STEPN; idx += 256) {
        int i = idx / STEPN, j = idx % STEPN;
        float s = 0.f;
        for (int k = 0; k < STEPN; ++k) s += Pb[i * STEPN + k] * Pb[j * STEPN + k];
        A[i][j] = (i == j) ? 0.f : s;
    }
    __syncthreads();
    if (tid < STEPN) {
        float s = 0.f;
        for (int j = 0; j < STEPN; ++j) s += A[tid][j];
        Asum[tid] = s;
    }
    __syncthreads();
    if (tid < STEPN) {
        int sdx = tid;
        bool m = false;
        for (int j = sdx + 1; j < STEPN; ++j)          // term1: i=sdx suppressed
            if (A[sdx][j] >= THRC && !(Asum[j] > Asum[sdx])) m = true;
        for (int i = 0; i < sdx; ++i)                  // term2: j=sdx suppressed
            if (A[i][sdx] >= THRC && (Asum[sdx] > Asum[i])) m = true;
        masks[b * STEPN + sdx] = m ? 1 : 0;
    }
}

// ---------------------------------------------------------------------------
// Masked semantic attention + build dec_in = [feat | embedded]: block per b
// ---------------------------------------------------------------------------
__global__ void sem_attn_kernel(const float* __restrict__ saq,     // (64,512) incl bias
                                const float* __restrict__ gk,      // (1280,512) incl bias
                                const float* __restrict__ w,       // (512)
                                const float* __restrict__ group,   // (1280,1536)
                                const int* __restrict__ masks,     // (64,20)
                                const float* __restrict__ embedded,// (64,512)
                                float* __restrict__ dec_in)        // (64,2048)
{
    int b = blockIdx.x;
    int tid = threadIdx.x, wave = tid >> 6, lane = tid & 63;
    __shared__ float lg[32];
    const float* qrow = saq + (size_t)b * HS;
    for (int s = wave; s < STEPN; s += 4) {
        const float* krow = gk + (size_t)(b * STEPN + s) * HS;
        float v = 0.f;
        for (int h = lane; h < HS; h += 64)
            v += w[h] * tanhf(qrow[h] + krow[h]);
        for (int off = 32; off > 0; off >>= 1) v += __shfl_down(v, off, 64);
        if (lane == 0) lg[s] = masks[b * STEPN + s] ? -1e9f : v;
    }
    __syncthreads();
    if (tid == 0) {
        float m = -1e30f;
        for (int s = 0; s < STEPN; ++s) m = fmaxf(m, lg[s]);
        float sum = 0.f;
        for (int s = 0; s < STEPN; ++s) { lg[s] = expf(lg[s] - m); sum += lg[s]; }
        float inv = 1.f / sum;
        for (int s = 0; s < STEPN; ++s) lg[s] *= inv;
    }
    __syncthreads();
    for (int d = tid; d < 3 * WS; d += 256) {
        float acc = 0.f;
        for (int s = 0; s < STEPN; ++s)
            acc += lg[s] * group[(size_t)(b * STEPN + s) * (3 * WS) + d];
        dec_in[(size_t)b * (4 * WS) + d] = acc;
    }
    for (int d = tid; d < WS; d += 256)
        dec_in[(size_t)b * (4 * WS) + 3 * WS + d] = embedded[(size_t)b * WS + d];
}

// ---------------------------------------------------------------------------
// LSTM pointwise; writes h_new/c_new to output and h_new into hcat[:,0:512]
// ---------------------------------------------------------------------------
__global__ void lstm_kernel(const float* __restrict__ gates, const float* __restrict__ c_prev,
                            float* __restrict__ out_h, float* __restrict__ out_c,
                            float* __restrict__ hcat)
{
    int idx = blockIdx.x * 256 + threadIdx.x;
    if (idx >= BB * HS) return;
    int b = idx >> 9, h = idx & (HS - 1);
    const float* g = gates + (size_t)b * 4 * HS;
    float ig = 1.f / (1.f + expf(-g[h]));
    float fg = 1.f / (1.f + expf(-g[HS + h]));
    float gg = tanhf(g[2 * HS + h]);
    float og = 1.f / (1.f + expf(-g[3 * HS + h]));
    float c = fg * c_prev[idx] + ig * gg;
    float hn = og * tanhf(c);
    out_h[idx] = hn;
    out_c[idx] = c;
    hcat[(size_t)b * (HS + 4 * WS) + h] = hn;
}

__global__ void copy_decin_hcat(const float* __restrict__ dec_in, float* __restrict__ hcat)
{
    int idx = blockIdx.x * 256 + threadIdx.x;
    if (idx >= BB * 4 * WS) return;
    int b = idx >> 11, c = idx & (4 * WS - 1);
    hcat[(size_t)b * (HS + 4 * WS) + HS + c] = dec_in[idx];
}

// ---------------------------------------------------------------------------
// Row log-softmax in place: block per row
// ---------------------------------------------------------------------------
__global__ void log_softmax_kernel(float* __restrict__ x, int N)
{
    int b = blockIdx.x, tid = threadIdx.x;
    float* row = x + (size_t)b * N;
    __shared__ float red[256];
    float m = -1e30f;
    for (int i = tid; i < N; i += 256) m = fmaxf(m, row[i]);
    red[tid] = m; __syncthreads();
    for (int s = 128; s > 0; s >>= 1) {
        if (tid < s) red[tid] = fmaxf(red[tid], red[tid + s]);
        __syncthreads();
    }
    m = red[0]; __syncthreads();
    float sum = 0.f;
    for (int i = tid; i < N; i += 256) sum += expf(row[i] - m);
    red[tid] = sum; __syncthreads();
    for (int s = 128; s > 0; s >>= 1) {
        if (tid < s) red[tid] += red[tid + s];
        __syncthreads();
    }
    float ls = logf(red[0]) + m;
    for (int i = tid; i < N; i += 256) row[i] = row[i] - ls;
}

// ---------------------------------------------------------------------------
extern "C" void kernel_launch(void* const* d_in, const int* in_sizes, int n_in,
                              void* d_out, int out_size, void* d_ws, size_t ws_size,
                              hipStream_t stream)
{
    const float* frame     = (const float*)d_in[0];
    const float* i3d       = (const float*)d_in[1];
    const float* obj       = (const float*)d_in[2];
    const float* phr_attns = (const float*)d_in[3];
    const float* phr_feats = (const float*)d_in[4];
    const float* last_h    = (const float*)d_in[5];
    const float* lstm_c    = (const float*)d_in[6];
    const float* embedded  = (const float*)d_in[7];
    const float* sp_Wq = (const float*)d_in[8];  const float* sp_bq = (const float*)d_in[9];
    const float* sp_Wk = (const float*)d_in[10]; const float* sp_bk = (const float*)d_in[11];
    const float* sp_w  = (const float*)d_in[12];
    const float* al_Wq = (const float*)d_in[13]; const float* al_bq = (const float*)d_in[14];
    const float* al_Wk = (const float*)d_in[15]; const float* al_bk = (const float*)d_in[16];
    const float* al_w  = (const float*)d_in[17];
    const float* sa_Wq = (const float*)d_in[18]; const float* sa_bq = (const float*)d_in[19];
    const float* sa_Wk = (const float*)d_in[20]; const float* sa_bk = (const float*)d_in[21];
    const float* sa_w  = (const float*)d_in[22];
    const float* cnn_W = (const float*)d_in[23]; const float* cnn_b = (const float*)d_in[24];
    const float* mot_W = (const float*)d_in[25]; const float* mot_b = (const float*)d_in[26];
    const float* fra_W = (const float*)d_in[27]; const float* fra_b = (const float*)d_in[28];
    const float* W_ih  = (const float*)d_in[29]; const float* b_ih  = (const float*)d_in[30];
    const float* W_hh  = (const float*)d_in[31]; const float* b_hh  = (const float*)d_in[32];
    const float* out_W = (const float*)d_in[33]; const float* out_b = (const float*)d_in[34];
    const float* wr_W  = (const float*)d_in[35]; const float* wr_b  = (const float*)d_in[36];

    float* out = (float*)d_out;
    float* out_wl = out;                       // (64,10000)
    float* out_h  = out + (size_t)BB * VOC;    // (64,512)
    float* out_c  = out_h + (size_t)BB * HS;   // (64,512)

    // workspace carve-up (floats)
    float* p = (float*)d_ws;
    float* q_sp    = p; p += BB * HS;               // 32768
    float* logits  = p; p += BB * TT * NB;          // 92160
    float* obj_att = p; p += BB * TT * FS;          // 2.62M
    float* kp      = p; p += BB * TT * HS;          // 1.31M
    float* alq     = p; p += BB * STEPN * HS;       // 655K
    float* semAB   = p; p += BB * STEPN * FS;       // 1.31M
    float* semfofm = p; p += BB * STEPN * 2 * FS;   // 2.62M
    float* group   = p; p += BB * STEPN * 3 * WS;   // 1.97M
    float* saq     = p; p += BB * HS;
    float* gk      = p; p += BB * STEPN * HS;
    int*   masks   = (int*)p; p += BB * STEPN;
    float* dec_in  = p; p += BB * 4 * WS;
    float* gates   = p; p += BB * 4 * HS;
    float* hcat    = p; p += BB * (HS + 4 * WS);
    float* dec_out = p; p += BB * HS;

    dim3 blk(256);
    auto gemm = [&](const float* A, int lda, const float* W, int ldb, const float* bias,
                    float* C, int ldc, int M, int N, int K, int flags) {
        dim3 grid((N + GBN - 1) / GBN, (M + GBM - 1) / GBM);
        hipLaunchKernelGGL(gemm_kernel, grid, blk, 0, stream,
                           A, lda, W, ldb, bias, C, ldc, M, N, K, flags);
    };

    // phr masks (independent)
    hipLaunchKernelGGL(phr_mask_kernel, dim3(BB), blk, 0, stream, phr_attns, masks);

    // q_sp = last_hidden @ sp_Wq + sp_bq
    gemm(last_h, HS, sp_Wq, HS, sp_bq, q_sp, HS, BB, HS, HS, 0);

    // spatial logits (fused GEMM + tanh + w-dot)
    hipMemsetAsync(logits, 0, (size_t)BB * TT * NB * sizeof(float), stream);
    hipLaunchKernelGGL(gemm_spatial_kernel, dim3(HS / GBN, BB * TT * NB / GBM), blk, 0, stream,
                       obj, sp_Wk, sp_bk, q_sp, sp_w, logits);
    // softmax over boxes + weighted sum -> obj_att
    hipLaunchKernelGGL(spatial_attn_kernel, dim3(BB * TT), blk, 0, stream, logits, obj, obj_att);

    // alignment 1: Q=phr_feats, K=obj_att -> sem_obj (semAB)
    gemm(obj_att, FS, al_Wk, HS, al_bk, kp, HS, BB * TT, HS, FS, 0);
    gemm(phr_feats, WS, al_Wq, HS, al_bq, alq, HS, BB * STEPN, HS, WS, 0);
    hipLaunchKernelGGL(align_kernel, dim3(BB * STEPN), blk, 0, stream,
                       alq, kp, al_w, obj_att, FS, semAB, FS, TT);
    // phr = sem_obj @ cnn_W + cnn_b  -> group cols 1024:1536
    gemm(semAB, FS, cnn_W, WS, cnn_b, group + 2 * WS, 3 * WS, BB * STEPN, WS, FS, 0);

    // alignment 2: Q=phr, K=i3d -> sem_i3d (semAB)
    gemm(group + 2 * WS, 3 * WS, al_Wq, HS, al_bq, alq, HS, BB * STEPN, HS, WS, 0);
    gemm(i3d, FS, al_Wk, HS, al_bk, kp, HS, BB * TT, HS, FS, 0);
    hipLaunchKernelGGL(align_kernel, dim3(BB * STEPN), blk, 0, stream,
                       alq, kp, al_w, i3d, FS, semAB, FS, TT);
    // phr_mot = sem_i3d @ mot_W + mot_b -> group cols 512:1024
    gemm(semAB, FS, mot_W, WS, mot_b, group + WS, 3 * WS, BB * STEPN, WS, FS, 0);

    // alignments 3+4: K=frame_feats (shared projection); Q=phr then Q=phr_mot
    gemm(frame, FS, al_Wk, HS, al_bk, kp, HS, BB * TT, HS, FS, 0);
    hipLaunchKernelGGL(align_kernel, dim3(BB * STEPN), blk, 0, stream,
                       alq, kp, al_w, frame, FS, semfofm, 2 * FS, TT);       // sem_fo (alq still = phr proj)
    gemm(group + WS, 3 * WS, al_Wq, HS, al_bq, alq, HS, BB * STEPN, HS, WS, 0);
    hipLaunchKernelGGL(align_kernel, dim3(BB * STEPN), blk, 0, stream,
                       alq, kp, al_w, frame, FS, semfofm + FS, 2 * FS, TT);  // sem_fm
    // phr_frame = [sem_fo|sem_fm] @ fra_W + fra_b -> group cols 0:512
    gemm(semfofm, 2 * FS, fra_W, WS, fra_b, group, 3 * WS, BB * STEPN, WS, 2 * FS, 0);

    // semantic attention
    gemm(last_h, HS, sa_Wq, HS, sa_bq, saq, HS, BB, HS, HS, 0);
    gemm(group, 3 * WS, sa_Wk, HS, sa_bk, gk, HS, BB * STEPN, HS, 3 * WS, 0);
    hipLaunchKernelGGL(sem_attn_kernel, dim3(BB), blk, 0, stream,
                       saq, gk, sa_w, group, masks, embedded, dec_in);

    // LSTM gates
    gemm(dec_in, 4 * WS, W_ih, 4 * HS, b_ih, gates, 4 * HS, BB, 4 * HS, 4 * WS, 0);
    gemm(last_h, HS, W_hh, 4 * HS, b_hh, gates, 4 * HS, BB, 4 * HS, HS, 2);  // accumulate
    hipLaunchKernelGGL(lstm_kernel, dim3((BB * HS + 255) / 256), blk, 0, stream,
                       gates, lstm_c, out_h, out_c, hcat);
    hipLaunchKernelGGL(copy_decin_hcat, dim3((BB * 4 * WS + 255) / 256), blk, 0, stream,
                       dec_in, hcat);

    // output head
    gemm(hcat, HS + 4 * WS, out_W, HS, out_b, dec_out, HS, BB, HS, HS + 4 * WS, 1); // tanh
    gemm(dec_out, HS, wr_W, VOC, wr_b, out_wl, VOC, BB, VOC, HS, 0);
    hipLaunchKernelGGL(log_softmax_kernel, dim3(BB), blk, 0, stream, out_wl, VOC);
}

// Round 2
// 1897.725 us; speedup vs baseline: 3.3520x; 3.3520x over previous
//
#include <hip/hip_runtime.h>
#include <math.h>

#define BB 64
#define TT 40
#define NB 36
#define FS 1024
#define WS 512
#define HS 512
#define VOC 10000
#define STEPN 20
#define THRC 0.2f

typedef __attribute__((ext_vector_type(8))) short bf16x8;
typedef __attribute__((ext_vector_type(4))) float f32x4;
typedef __attribute__((ext_vector_type(8))) unsigned short u16x8;
typedef __attribute__((ext_vector_type(4))) unsigned short u16x4;

__device__ __forceinline__ unsigned short f2bf(float f) {
    unsigned int u = __float_as_uint(f);
    u = (u + 0x7FFFu + ((u >> 16) & 1u)) >> 16;   // RNE
    return (unsigned short)u;
}

// ---------------------------------------------------------------------------
// Pack fp32 weight W (K,N) row-major, leading dim ldw, into bf16 MFMA B-frag
// order: out[(((nt*Ksteps + ks)*64 + lane)*8 + j] = W[ks*32+(lane>>4)*8+j][nt*16+(lane&15)]
// Launch: (Npad/16)*(K/32)*64 threads total, 256/block.
// ---------------------------------------------------------------------------
__global__ void pack_b_kernel(const float* __restrict__ W, int K, int N, int ldw,
                              unsigned short* __restrict__ out, int Ksteps)
{
    int g = blockIdx.x * 256 + threadIdx.x;
    int lane = g & 63;
    int slot = g >> 6;
    int ks = slot % Ksteps;
    int nt = slot / Ksteps;
    int n = nt * 16 + (lane & 15);
    int kbase = ks * 32 + (lane >> 4) * 8;
    u16x8 v;
#pragma unroll
    for (int j = 0; j < 8; ++j) {
        float x = (n < N) ? W[(size_t)(kbase + j) * ldw + n] : 0.f;
        v[j] = f2bf(x);
    }
    *(u16x8*)(out + (size_t)g * 8) = v;
}

// ---------------------------------------------------------------------------
// Generic bf16-MFMA GEMM: C[M,N] = A_fp32[M,K](lda) @ Bpacked + bias
// grid(Npad/512, M/64), 512 threads. flags: bit0=tanh bit1=accum. K%32==0, M%64==0.
// ---------------------------------------------------------------------------
__global__ __launch_bounds__(512)
void gemm_mfma(const float* __restrict__ A, int lda,
               const unsigned short* __restrict__ Bp,
               const float* __restrict__ bias,
               float* __restrict__ C, int ldc,
               int M, int N, int K, int flags)
{
    __shared__ __align__(16) unsigned short As[64 * 56];
    const int tid = threadIdx.x;
    const int wave = tid >> 6, lane = tid & 63;
    const int quad = lane >> 4, l16 = lane & 15;
    const int bm = blockIdx.y * 64;
    const int Ksteps = K >> 5;
    const size_t ntile0 = (size_t)blockIdx.x * 32 + wave * 4;

    f32x4 acc[4][4];
    const f32x4 z = {0.f, 0.f, 0.f, 0.f};
#pragma unroll
    for (int mt = 0; mt < 4; ++mt)
#pragma unroll
        for (int jt = 0; jt < 4; ++jt) acc[mt][jt] = z;

    const int srow = tid >> 3, scol = (tid & 7) * 4;
    const float* Arow = A + (size_t)(bm + srow) * lda + scol;
    unsigned short* sdst = &As[srow * 56 + scol];

    for (int ks = 0; ks < Ksteps; ++ks) {
        __syncthreads();
        float4 av = *(const float4*)(Arow + ks * 32);
        u16x4 sv = { f2bf(av.x), f2bf(av.y), f2bf(av.z), f2bf(av.w) };
        *(u16x4*)sdst = sv;
        __syncthreads();
        bf16x8 afr[4], bfr[4];
#pragma unroll
        for (int mt = 0; mt < 4; ++mt)
            afr[mt] = *(const bf16x8*)&As[(mt * 16 + l16) * 56 + quad * 8];
#pragma unroll
        for (int jt = 0; jt < 4; ++jt)
            bfr[jt] = *(const bf16x8*)(Bp + (((ntile0 + jt) * Ksteps + ks) * 64 + lane) * 8);
#pragma unroll
        for (int mt = 0; mt < 4; ++mt)
#pragma unroll
            for (int jt = 0; jt < 4; ++jt)
                acc[mt][jt] = __builtin_amdgcn_mfma_f32_16x16x32_bf16(
                    afr[mt], bfr[jt], acc[mt][jt], 0, 0, 0);
    }

#pragma unroll
    for (int mt = 0; mt < 4; ++mt) {
        int row = bm + mt * 16 + quad * 4;
#pragma unroll
        for (int jt = 0; jt < 4; ++jt) {
            int col = blockIdx.x * 512 + (wave * 4 + jt) * 16 + l16;
            if (col < N) {
                float bv = bias ? bias[col] : 0.f;
#pragma unroll
                for (int r = 0; r < 4; ++r) {
                    float v = acc[mt][jt][r] + bv;
                    size_t o = (size_t)(row + r) * ldc + col;
                    if (flags & 2) v += C[o];
                    if (flags & 1) v = tanhf(v);
                    C[o] = v;
                }
            }
        }
    }
}

// ---------------------------------------------------------------------------
// Fused spatial logits: same GEMM core (N=512 fixed, grid(1, M/64)) but the
// epilogue computes logits[row] = sum_n w[n]*tanh(acc + bk[n] + q[b][n]).
// ---------------------------------------------------------------------------
__global__ __launch_bounds__(512)
void gemm_mfma_spatial(const float* __restrict__ A,            // obj (M,1024)
                       const unsigned short* __restrict__ Bp,  // packed sp_Wk
                       const float* __restrict__ bk,
                       const float* __restrict__ q,            // (64,512) incl bq
                       const float* __restrict__ w,
                       float* __restrict__ logits)
{
    __shared__ __align__(16) unsigned short As[64 * 56];
    __shared__ float slog[64];
    const int tid = threadIdx.x;
    const int wave = tid >> 6, lane = tid & 63;
    const int quad = lane >> 4, l16 = lane & 15;
    const int bm = blockIdx.y * 64;
    const int Ksteps = 32;                      // K = 1024
    const size_t ntile0 = (size_t)wave * 4;

    if (tid < 64) slog[tid] = 0.f;

    f32x4 acc[4][4];
    const f32x4 z = {0.f, 0.f, 0.f, 0.f};
#pragma unroll
    for (int mt = 0; mt < 4; ++mt)
#pragma unroll
        for (int jt = 0; jt < 4; ++jt) acc[mt][jt] = z;

    const int srow = tid >> 3, scol = (tid & 7) * 4;
    const float* Arow = A + (size_t)(bm + srow) * 1024 + scol;
    unsigned short* sdst = &As[srow * 56 + scol];

    for (int ks = 0; ks < Ksteps; ++ks) {
        __syncthreads();
        float4 av = *(const float4*)(Arow + ks * 32);
        u16x4 sv = { f2bf(av.x), f2bf(av.y), f2bf(av.z), f2bf(av.w) };
        *(u16x4*)sdst = sv;
        __syncthreads();
        bf16x8 afr[4], bfr[4];
#pragma unroll
        for (int mt = 0; mt < 4; ++mt)
            afr[mt] = *(const bf16x8*)&As[(mt * 16 + l16) * 56 + quad * 8];
#pragma unroll
        for (int jt = 0; jt < 4; ++jt)
            bfr[jt] = *(const bf16x8*)(Bp + (((ntile0 + jt) * Ksteps + ks) * 64 + lane) * 8);
#pragma unroll
        for (int mt = 0; mt < 4; ++mt)
#pragma unroll
            for (int jt = 0; jt < 4; ++jt)
                acc[mt][jt] = __builtin_amdgcn_mfma_f32_16x16x32_bf16(
                    afr[mt], bfr[jt], acc[mt][jt], 0, 0, 0);
    }

#pragma unroll
    for (int mt = 0; mt < 4; ++mt) {
        float rp[4] = {0.f, 0.f, 0.f, 0.f};
#pragma unroll
        for (int jt = 0; jt < 4; ++jt) {
            int col = (wave * 4 + jt) * 16 + l16;
            float wv = w[col], bkv = bk[col];
#pragma unroll
            for (int r = 0; r < 4; ++r) {
                int row = bm + mt * 16 + quad * 4 + r;
                int b = row / (TT * NB);
                rp[r] += wv * tanhf(acc[mt][jt][r] + bkv + q[b * HS + col]);
            }
        }
#pragma unroll
        for (int m = 1; m < 16; m <<= 1)
#pragma unroll
            for (int r = 0; r < 4; ++r) rp[r] += __shfl_xor(rp[r], m, 64);
        if (l16 == 0)
#pragma unroll
            for (int r = 0; r < 4; ++r)
                atomicAdd(&slog[mt * 16 + quad * 4 + r], rp[r]);
    }
    __syncthreads();
    if (tid < 64) logits[bm + tid] = slog[tid];
}

// ---------------------------------------------------------------------------
// Per-frame box softmax + weighted sum: one block per bt (2560 blocks)
// ---------------------------------------------------------------------------
__global__ void spatial_attn_kernel(const float* __restrict__ logits,
                                    const float* __restrict__ obj,
                                    float* __restrict__ obj_att)
{
    int bt = blockIdx.x, tid = threadIdx.x;
    __shared__ float a[NB];
    if (tid < NB) a[tid] = logits[bt * NB + tid];
    __syncthreads();
    if (tid == 0) {
        float m = -1e30f;
        for (int n = 0; n < NB; ++n) m = fmaxf(m, a[n]);
        float s = 0.f;
        for (int n = 0; n < NB; ++n) { a[n] = expf(a[n] - m); s += a[n]; }
        float inv = 1.f / s;
        for (int n = 0; n < NB; ++n) a[n] *= inv;
    }
    __syncthreads();
    for (int d = tid; d < FS; d += 256) {
        float acc = 0.f;
        for (int n = 0; n < NB; ++n)
            acc += a[n] * obj[((size_t)bt * NB + n) * FS + d];
        obj_att[(size_t)bt * FS + d] = acc;
    }
}

// ---------------------------------------------------------------------------
// Fused additive alignment: per (b,s) block.
// ---------------------------------------------------------------------------
__global__ void align_kernel(const float* __restrict__ q,
                             const float* __restrict__ kp,
                             const float* __restrict__ w,
                             const float* __restrict__ Km,
                             int D, float* __restrict__ out, int ldo, int Tn)
{
    int bs = blockIdx.x;
    int b = bs / STEPN;
    int tid = threadIdx.x, wave = tid >> 6, lane = tid & 63;
    __shared__ float lg[64];
    const float* qrow = q + (size_t)bs * HS;
    for (int t = wave; t < Tn; t += 4) {
        const float* krow = kp + (size_t)(b * Tn + t) * HS;
        float s = 0.f;
        for (int h = lane; h < HS; h += 64)
            s += w[h] * tanhf(qrow[h] + krow[h]);
        for (int off = 32; off > 0; off >>= 1) s += __shfl_down(s, off, 64);
        if (lane == 0) lg[t] = s;
    }
    __syncthreads();
    if (tid == 0) {
        float m = -1e30f;
        for (int t = 0; t < Tn; ++t) m = fmaxf(m, lg[t]);
        float s = 0.f;
        for (int t = 0; t < Tn; ++t) { lg[t] = expf(lg[t] - m); s += lg[t]; }
        float inv = 1.f / s;
        for (int t = 0; t < Tn; ++t) lg[t] *= inv;
    }
    __syncthreads();
    for (int d = tid; d < D; d += 256) {
        float acc = 0.f;
        for (int t = 0; t < Tn; ++t)
            acc += lg[t] * Km[(size_t)(b * Tn + t) * D + d];
        out[(size_t)bs * ldo + d] = acc;
    }
}

// ---------------------------------------------------------------------------
// phr_masks NMS: one block per batch
// ---------------------------------------------------------------------------
__global__ void phr_mask_kernel(const float* __restrict__ P, int* __restrict__ masks)
{
    int b = blockIdx.x, tid = threadIdx.x;
    __shared__ float A[STEPN][STEPN];
    __shared__ float Asum[STEPN];
    const float* Pb = P + (size_t)b * STEPN * STEPN;
    for (int idx = tid; idx < STEPN * STEPN; idx += 256) {
        int i = idx / STEPN, j = idx % STEPN;
        float s = 0.f;
        for (int k = 0; k < STEPN; ++k) s += Pb[i * STEPN + k] * Pb[j * STEPN + k];
        A[i][j] = (i == j) ? 0.f : s;
    }
    __syncthreads();
    if (tid < STEPN) {
        float s = 0.f;
        for (int j = 0; j < STEPN; ++j) s += A[tid][j];
        Asum[tid] = s;
    }
    __syncthreads();
    if (tid < STEPN) {
        int sdx = tid;
        bool m = false;
        for (int j = sdx + 1; j < STEPN; ++j)
            if (A[sdx][j] >= THRC && !(Asum[j] > Asum[sdx])) m = true;
        for (int i = 0; i < sdx; ++i)
            if (A[i][sdx] >= THRC && (Asum[sdx] > Asum[i])) m = true;
        masks[b * STEPN + sdx] = m ? 1 : 0;
    }
}

// ---------------------------------------------------------------------------
// Masked semantic attention + build dec_in = [feat | embedded]
// ---------------------------------------------------------------------------
__global__ void sem_attn_kernel(const float* __restrict__ saq,
                                const float* __restrict__ gk,
                                const float* __restrict__ w,
                                const float* __restrict__ group,
                                const int* __restrict__ masks,
                                const float* __restrict__ embedded,
                                float* __restrict__ dec_in)
{
    int b = blockIdx.x;
    int tid = threadIdx.x, wave = tid >> 6, lane = tid & 63;
    __shared__ float lg[32];
    const float* qrow = saq + (size_t)b * HS;
    for (int s = wave; s < STEPN; s += 4) {
        const float* krow = gk + (size_t)(b * STEPN + s) * HS;
        float v = 0.f;
        for (int h = lane; h < HS; h += 64)
            v += w[h] * tanhf(qrow[h] + krow[h]);
        for (int off = 32; off > 0; off >>= 1) v += __shfl_down(v, off, 64);
        if (lane == 0) lg[s] = masks[b * STEPN + s] ? -1e9f : v;
    }
    __syncthreads();
    if (tid == 0) {
        float m = -1e30f;
        for (int s = 0; s < STEPN; ++s) m = fmaxf(m, lg[s]);
        float sum = 0.f;
        for (int s = 0; s < STEPN; ++s) { lg[s] = expf(lg[s] - m); sum += lg[s]; }
        float inv = 1.f / sum;
        for (int s = 0; s < STEPN; ++s) lg[s] *= inv;
    }
    __syncthreads();
    for (int d = tid; d < 3 * WS; d += 256) {
        float acc = 0.f;
        for (int s = 0; s < STEPN; ++s)
            acc += lg[s] * group[(size_t)(b * STEPN + s) * (3 * WS) + d];
        dec_in[(size_t)b * (4 * WS) + d] = acc;
    }
    for (int d = tid; d < WS; d += 256)
        dec_in[(size_t)b * (4 * WS) + 3 * WS + d] = embedded[(size_t)b * WS + d];
}

// ---------------------------------------------------------------------------
// LSTM pointwise
// ---------------------------------------------------------------------------
__global__ void lstm_kernel(const float* __restrict__ gates, const float* __restrict__ c_prev,
                            float* __restrict__ out_h, float* __restrict__ out_c,
                            float* __restrict__ hcat)
{
    int idx = blockIdx.x * 256 + threadIdx.x;
    if (idx >= BB * HS) return;
    int b = idx >> 9, h = idx & (HS - 1);
    const float* g = gates + (size_t)b * 4 * HS;
    float ig = 1.f / (1.f + expf(-g[h]));
    float fg = 1.f / (1.f + expf(-g[HS + h]));
    float gg = tanhf(g[2 * HS + h]);
    float og = 1.f / (1.f + expf(-g[3 * HS + h]));
    float c = fg * c_prev[idx] + ig * gg;
    float hn = og * tanhf(c);
    out_h[idx] = hn;
    out_c[idx] = c;
    hcat[(size_t)b * (HS + 4 * WS) + h] = hn;
}

__global__ void copy_decin_hcat(const float* __restrict__ dec_in, float* __restrict__ hcat)
{
    int idx = blockIdx.x * 256 + threadIdx.x;
    if (idx >= BB * 4 * WS) return;
    int b = idx >> 11, c = idx & (4 * WS - 1);
    hcat[(size_t)b * (HS + 4 * WS) + HS + c] = dec_in[idx];
}

// ---------------------------------------------------------------------------
// Row log-softmax in place
// ---------------------------------------------------------------------------
__global__ void log_softmax_kernel(float* __restrict__ x, int N)
{
    int b = blockIdx.x, tid = threadIdx.x;
    float* row = x + (size_t)b * N;
    __shared__ float red[256];
    float m = -1e30f;
    for (int i = tid; i < N; i += 256) m = fmaxf(m, row[i]);
    red[tid] = m; __syncthreads();
    for (int s = 128; s > 0; s >>= 1) {
        if (tid < s) red[tid] = fmaxf(red[tid], red[tid + s]);
        __syncthreads();
    }
    m = red[0]; __syncthreads();
    float sum = 0.f;
    for (int i = tid; i < N; i += 256) sum += expf(row[i] - m);
    red[tid] = sum; __syncthreads();
    for (int s = 128; s > 0; s >>= 1) {
        if (tid < s) red[tid] += red[tid + s];
        __syncthreads();
    }
    float ls = logf(red[0]) + m;
    for (int i = tid; i < N; i += 256) row[i] = row[i] - ls;
}

// ---------------------------------------------------------------------------
extern "C" void kernel_launch(void* const* d_in, const int* in_sizes, int n_in,
                              void* d_out, int out_size, void* d_ws, size_t ws_size,
                              hipStream_t stream)
{
    const float* frame     = (const float*)d_in[0];
    const float* i3d       = (const float*)d_in[1];
    const float* obj       = (const float*)d_in[2];
    const float* phr_attns = (const float*)d_in[3];
    const float* phr_feats = (const float*)d_in[4];
    const float* last_h    = (const float*)d_in[5];
    const float* lstm_c    = (const float*)d_in[6];
    const float* embedded  = (const float*)d_in[7];
    const float* sp_Wq = (const float*)d_in[8];  const float* sp_bq = (const float*)d_in[9];
    const float* sp_Wk = (const float*)d_in[10]; const float* sp_bk = (const float*)d_in[11];
    const float* sp_w  = (const float*)d_in[12];
    const float* al_Wq = (const float*)d_in[13]; const float* al_bq = (const float*)d_in[14];
    const float* al_Wk = (const float*)d_in[15]; const float* al_bk = (const float*)d_in[16];
    const float* al_w  = (const float*)d_in[17];
    const float* sa_Wq = (const float*)d_in[18]; const float* sa_bq = (const float*)d_in[19];
    const float* sa_Wk = (const float*)d_in[20]; const float* sa_bk = (const float*)d_in[21];
    const float* sa_w  = (const float*)d_in[22];
    const float* cnn_W = (const float*)d_in[23]; const float* cnn_b = (const float*)d_in[24];
    const float* mot_W = (const float*)d_in[25]; const float* mot_b = (const float*)d_in[26];
    const float* fra_W = (const float*)d_in[27]; const float* fra_b = (const float*)d_in[28];
    const float* W_ih  = (const float*)d_in[29]; const float* b_ih  = (const float*)d_in[30];
    const float* W_hh  = (const float*)d_in[31]; const float* b_hh  = (const float*)d_in[32];
    const float* out_W = (const float*)d_in[33]; const float* out_b = (const float*)d_in[34];
    const float* wr_W  = (const float*)d_in[35]; const float* wr_b  = (const float*)d_in[36];

    float* out = (float*)d_out;
    float* out_wl = out;
    float* out_h  = out + (size_t)BB * VOC;
    float* out_c  = out_h + (size_t)BB * HS;

    // ---- workspace carve-up (floats) ----
    float* p = (float*)d_ws;
    float* q_sp    = p; p += BB * HS;
    float* logits  = p; p += BB * TT * NB;
    float* obj_att = p; p += BB * TT * FS;          // later: wr_W pack (same bytes)
    float* kp      = p; p += BB * TT * HS;          // later: W_hh + out_W packs
    float* alq     = p; p += BB * STEPN * HS;
    float* semAB   = p; p += BB * STEPN * FS;
    float* semfofm = p; p += BB * STEPN * 2 * FS;   // later: W_ih pack
    float* group   = p; p += BB * STEPN * 3 * WS;
    float* saq     = p; p += BB * HS;
    float* gk      = p; p += BB * STEPN * HS;
    int*   masks   = (int*)p; p += BB * STEPN;
    float* dec_in  = p; p += BB * 4 * WS;
    float* gates   = p; p += BB * 4 * HS;
    float* hcat    = p; p += BB * (HS + 4 * WS);
    float* dec_out = p; p += BB * HS;
    // persistent packed weights (bf16)
    unsigned short* spq_p = (unsigned short*)p; p += (512 * 512) / 2;
    unsigned short* spk_p = (unsigned short*)p; p += (1024 * 512) / 2;
    unsigned short* alqw_p = (unsigned short*)p; p += (512 * 512) / 2;
    unsigned short* alkw_p = (unsigned short*)p; p += (1024 * 512) / 2;
    unsigned short* saqw_p = (unsigned short*)p; p += (512 * 512) / 2;
    unsigned short* sakw_p = (unsigned short*)p; p += (1536 * 512) / 2;
    unsigned short* cnn_p = (unsigned short*)p; p += (1024 * 512) / 2;
    unsigned short* mot_p = (unsigned short*)p; p += (1024 * 512) / 2;
    unsigned short* fra_p = (unsigned short*)p; p += (2048 * 512) / 2;
    // overlaid packs (launched after last reader of the region)
    unsigned short* wr_p  = (unsigned short*)obj_att;   // 512x10240 bf16 = 10.0 MB
    unsigned short* wih_p = (unsigned short*)semfofm;   // 2048x2048 bf16 = 8.0 MB
    unsigned short* whh_p = (unsigned short*)kp;        // 512x2048 bf16
    unsigned short* outw_p = (unsigned short*)(kp + 524288); // 2560x512 bf16

    dim3 blk256(256), blk512(512);
    auto pack = [&](const float* W, int K, int N, int ldw, unsigned short* dst, int Npad) {
        int slots = (Npad / 16) * (K / 32);
        hipLaunchKernelGGL(pack_b_kernel, dim3(slots * 64 / 256), blk256, 0, stream,
                           W, K, N, ldw, dst, K / 32);
    };
    auto mm = [&](const float* A, int lda, const unsigned short* Bp, const float* bias,
                  float* C, int ldc, int M, int N, int K, int flags, int Npad) {
        hipLaunchKernelGGL(gemm_mfma, dim3(Npad / 512, M / 64), blk512, 0, stream,
                           A, lda, Bp, bias, C, ldc, M, N, K, flags);
    };

    // ---- persistent weight packs ----
    pack(sp_Wq, 512, 512, 512, spq_p, 512);
    pack(sp_Wk, 1024, 512, 512, spk_p, 512);
    pack(al_Wq, 512, 512, 512, alqw_p, 512);
    pack(al_Wk, 1024, 512, 512, alkw_p, 512);
    pack(sa_Wq, 512, 512, 512, saqw_p, 512);
    pack(sa_Wk, 1536, 512, 512, sakw_p, 512);
    pack(cnn_W, 1024, 512, 512, cnn_p, 512);
    pack(mot_W, 1024, 512, 512, mot_p, 512);
    pack(fra_W, 2048, 512, 512, fra_p, 512);

    hipLaunchKernelGGL(phr_mask_kernel, dim3(BB), blk256, 0, stream, phr_attns, masks);

    // spatial attention over boxes
    mm(last_h, HS, spq_p, sp_bq, q_sp, HS, BB, HS, HS, 0, 512);
    hipLaunchKernelGGL(gemm_mfma_spatial, dim3(1, (BB * TT * NB) / 64), blk512, 0, stream,
                       obj, spk_p, sp_bk, q_sp, sp_w, logits);
    hipLaunchKernelGGL(spatial_attn_kernel, dim3(BB * TT), blk256, 0, stream,
                       logits, obj, obj_att);

    // alignment 1: Q=phr_feats, K=obj_att
    mm(obj_att, FS, alkw_p, al_bk, kp, HS, BB * TT, HS, FS, 0, 512);
    mm(phr_feats, WS, alqw_p, al_bq, alq, HS, BB * STEPN, HS, WS, 0, 512);
    hipLaunchKernelGGL(align_kernel, dim3(BB * STEPN), blk256, 0, stream,
                       alq, kp, al_w, obj_att, FS, semAB, FS, TT);
    pack(wr_W, 512, VOC, VOC, wr_p, 10240);          // obj_att now free
    mm(semAB, FS, cnn_p, cnn_b, group + 2 * WS, 3 * WS, BB * STEPN, WS, FS, 0, 512); // phr

    // alignment 2: Q=phr, K=i3d
    mm(group + 2 * WS, 3 * WS, alqw_p, al_bq, alq, HS, BB * STEPN, HS, WS, 0, 512);
    mm(i3d, FS, alkw_p, al_bk, kp, HS, BB * TT, HS, FS, 0, 512);
    hipLaunchKernelGGL(align_kernel, dim3(BB * STEPN), blk256, 0, stream,
                       alq, kp, al_w, i3d, FS, semAB, FS, TT);
    mm(semAB, FS, mot_p, mot_b, group + WS, 3 * WS, BB * STEPN, WS, FS, 0, 512);     // phr_mot

    // alignments 3+4: K=frame (shared k-projection); Q=phr then Q=phr_mot
    mm(frame, FS, alkw_p, al_bk, kp, HS, BB * TT, HS, FS, 0, 512);
    hipLaunchKernelGGL(align_kernel, dim3(BB * STEPN), blk256, 0, stream,
                       alq, kp, al_w, frame, FS, semfofm, 2 * FS, TT);               // sem_fo
    mm(group + WS, 3 * WS, alqw_p, al_bq, alq, HS, BB * STEPN, HS, WS, 0, 512);
    hipLaunchKernelGGL(align_kernel, dim3(BB * STEPN), blk256, 0, stream,
                       alq, kp, al_w, frame, FS, semfofm + FS, 2 * FS, TT);          // sem_fm
    mm(semfofm, 2 * FS, fra_p, fra_b, group, 3 * WS, BB * STEPN, WS, 2 * FS, 0, 512);

    // overlaid packs now that semfofm / kp are free
    pack(W_ih, 2048, 2048, 2048, wih_p, 2048);
    pack(W_hh, 512, 2048, 2048, whh_p, 2048);
    pack(out_W, 2560, 512, 512, outw_p, 512);

    // semantic attention
    mm(last_h, HS, saqw_p, sa_bq, saq, HS, BB, HS, HS, 0, 512);
    mm(group, 3 * WS, sakw_p, sa_bk, gk, HS, BB * STEPN, HS, 3 * WS, 0, 512);
    hipLaunchKernelGGL(sem_attn_kernel, dim3(BB), blk256, 0, stream,
                       saq, gk, sa_w, group, masks, embedded, dec_in);

    // LSTM
    mm(dec_in, 4 * WS, wih_p, b_ih, gates, 4 * HS, BB, 4 * HS, 4 * WS, 0, 2048);
    mm(last_h, HS, whh_p, b_hh, gates, 4 * HS, BB, 4 * HS, HS, 2, 2048);   // accumulate
    hipLaunchKernelGGL(lstm_kernel, dim3((BB * HS + 255) / 256), blk256, 0, stream,
                       gates, lstm_c, out_h, out_c, hcat);
    hipLaunchKernelGGL(copy_decin_hcat, dim3((BB * 4 * WS + 255) / 256), blk256, 0, stream,
                       dec_in, hcat);

    // output head
    mm(hcat, HS + 4 * WS, outw_p, out_b, dec_out, HS, BB, HS, HS + 4 * WS, 1, 512); // tanh
    mm(dec_out, HS, wr_p, wr_b, out_wl, VOC, BB, VOC, HS, 0, 10240);
    hipLaunchKernelGGL(log_softmax_kernel, dim3(BB), blk256, 0, stream, out_wl, VOC);
}